// Round 5
// baseline (553.538 us; speedup 1.0000x reference)
//
#include <hip/hip_runtime.h>
#include <hip/hip_bf16.h>
#include <math.h>

#define NEG_SLOPE 0.2f

typedef unsigned short ushortT;
typedef __attribute__((ext_vector_type(8))) short short8;   // 8 bf16 = 4 VGPRs (MFMA A/B frag)
typedef __attribute__((ext_vector_type(4))) float f32x4;    // MFMA C/D frag
typedef __attribute__((ext_vector_type(4), aligned(4))) int   int4u;   // 4B-aligned int4 load

static __device__ __forceinline__ float leaky(float x){ return x > 0.f ? x : NEG_SLOPE * x; }
static __device__ __forceinline__ float elu(float x){ return x > 0.f ? x : (__expf(x) - 1.f); }

// bf16 helpers: RNE pack, exact unpack
static __device__ __forceinline__ ushortT f2bf(float f){
  unsigned u = __float_as_uint(f);
  u += 0x7fff + ((u >> 16) & 1);
  return (ushortT)(u >> 16);
}
static __device__ __forceinline__ float bf2f(ushortT h){ return __uint_as_float((unsigned)h << 16); }
static __device__ __forceinline__ float bf_lo(unsigned u){ return __uint_as_float(u << 16); }
static __device__ __forceinline__ float bf_hi(unsigned u){ return __uint_as_float(u & 0xffff0000u); }

// A-plane layout: elem (row,k) -> [ (k/32)*Mpad + row ]*32 + k%32
// B-plane layout: [(ntile*8 + t)*64 + lane]*8 (contiguous 1KB per wave frag)

// ---------------- edge sort by dst (counting sort) ----------------
__global__ void hist_kernel(const int* __restrict__ dst, int E, int* __restrict__ counts){
  int i = blockIdx.x*blockDim.x + threadIdx.x;
  if(i < E) atomicAdd(&counts[dst[i]], 1);
}

__global__ void scan1_kernel(const int* __restrict__ counts, int N,
                             int* __restrict__ offsets, int* __restrict__ blocksums){
  __shared__ int sdata[1024];
  int i = blockIdx.x*1024 + threadIdx.x;
  int v = (i<N) ? counts[i] : 0;
  sdata[threadIdx.x] = v;
  __syncthreads();
  for(int off=1; off<1024; off<<=1){
    int t = (threadIdx.x >= off) ? sdata[threadIdx.x-off] : 0;
    __syncthreads();
    sdata[threadIdx.x] += t;
    __syncthreads();
  }
  if(i<N) offsets[i] = sdata[threadIdx.x] - v;
  if(threadIdx.x==1023) blocksums[blockIdx.x] = sdata[1023];
}

// scan2 folded in: each block serially sums blocksums[0..blockIdx) (<=48 ints, L2-hot,
// wave-uniform scalar loop) — saves one dependent dispatch.
__global__ void scan3_kernel(int* __restrict__ offsets, const int* __restrict__ blocksums,
                             int N, int E, int* __restrict__ cursor){
  __shared__ int sbase;
  if(threadIdx.x == 0){
    int s = 0;
    for(int i=0;i<(int)blockIdx.x;i++) s += blocksums[i];
    sbase = s;
  }
  __syncthreads();
  int i = blockIdx.x*1024 + threadIdx.x;
  if(i < N){
    int o = offsets[i] + sbase;
    offsets[i] = o;
    cursor[i] = o;
  }
  if(i == 0) offsets[N] = E;
}

__global__ void scatter_kernel(const int* __restrict__ src, const int* __restrict__ dst, int E,
                               int* __restrict__ cursor, int* __restrict__ ssrc){
  int i = blockIdx.x*blockDim.x + threadIdx.x;
  if(i < E){
    int d = dst[i];
    int p = atomicAdd(&cursor[d], 1);
    ssrc[p] = src[i];
  }
}

// ---------------- fused packing: xsplit (blocks [0,xblocks)) + 3x wsplit (next 96) ----------------
__global__ __launch_bounds__(256) void pack_all(
    const float* __restrict__ x, int M, int Mpad, int xblocks,
    ushortT* __restrict__ Xh, ushortT* __restrict__ Xl,
    const float* __restrict__ W0, const float* __restrict__ W1, const float* __restrict__ W2,
    ushortT* __restrict__ Wph0, ushortT* __restrict__ Wpl0,
    ushortT* __restrict__ Wph1, ushortT* __restrict__ Wpl1,
    ushortT* __restrict__ Wph2, ushortT* __restrict__ Wpl2){
  int b = blockIdx.x;
  if(b < xblocks){
    // ---- x split fp32 [M][256] -> A-plane layout [t][Mpad][32] ----
    int idx = b*256 + threadIdx.x;
    if(idx >= 8*Mpad) return;
    int t = idx / Mpad, m = idx - t*Mpad;
    size_t base = (size_t)idx * 32;
    if(m < M){
      const float* xr = &x[(size_t)m*256 + t*32];
      #pragma unroll
      for(int c=0;c<4;c++){
        float4 v0 = *(const float4*)&xr[c*8];
        float4 v1 = *(const float4*)&xr[c*8+4];
        float vv[8] = {v0.x,v0.y,v0.z,v0.w,v1.x,v1.y,v1.z,v1.w};
        ushortT h[8], l[8];
        #pragma unroll
        for(int j=0;j<8;j++){
          h[j] = f2bf(vv[j]);
          l[j] = f2bf(vv[j] - bf2f(h[j]));
        }
        *(short8*)&Xh[base + c*8] = *(short8*)h;
        *(short8*)&Xl[base + c*8] = *(short8*)l;
      }
    } else {
      short8 z = {0,0,0,0,0,0,0,0};
      #pragma unroll
      for(int c=0;c<4;c++){ *(short8*)&Xh[base + c*8] = z; *(short8*)&Xl[base + c*8] = z; }
    }
  } else {
    // ---- W split: W[K=256, N] -> packed fragment order [16 ntiles] ----
    int wb = b - xblocks;            // 0..95
    int which = wb >> 5;             // 0,1,2
    const float* W = (which==0) ? W0 : (which==1) ? W1 : W2;
    ushortT* Wh = (which==0) ? Wph0 : (which==1) ? Wph1 : Wph2;
    ushortT* Wl = (which==0) ? Wpl0 : (which==1) ? Wpl1 : Wpl2;
    int Nn = (which==2) ? 160 : 256;
    int idx = (wb & 31)*256 + threadIdx.x;   // < 8192
    int lane = idx & 63;
    int t  = (idx >> 6) & 7;
    int nt = idx >> 9;
    int l15 = lane & 15, quad = lane >> 4;
    int n = nt*16 + l15;
    ushortT h[8], l[8];
    #pragma unroll
    for(int j=0;j<8;j++){
      int k = t*32 + quad*8 + j;
      float v = (n < Nn) ? W[(size_t)k*Nn + n] : 0.f;
      h[j] = f2bf(v);
      l[j] = f2bf(v - bf2f(h[j]));
    }
    *(short8*)&Wh[(size_t)idx*8] = *(short8*)h;
    *(short8*)&Wl[(size_t)idx*8] = *(short8*)l;
  }
}

// ---------------- bf16x3 MFMA GEMM: block = 64 rows x full N; 4 waves side-by-side in N ----
// 64-row M-tile: per t-iter 16 loads feed 48 MFMAs (vs 12:24 at 32 rows) and halves the
// per-gemm B re-read L2 traffic (782 blocks x 256KB). A-tile 8KB/t stays L1-resident.
// ntiles: real 16-col n-tiles (16 for N=256, 10 for N=160); waves beyond skip B+MFMA.
__global__ __launch_bounds__(256) void gemm_packed(
    const ushortT* __restrict__ Ah, const ushortT* __restrict__ Al,
    const ushortT* __restrict__ Bh, const ushortT* __restrict__ Bl,
    ushortT* __restrict__ Cm, int M, int Mpad, int N, int ntiles,
    const float* __restrict__ al, const float* __restrict__ ar,
    float* __restrict__ el, float* __restrict__ er){
  const int lane = threadIdx.x & 63;
  const int wv   = threadIdx.x >> 6;
  const int l15  = lane & 15, quad = lane >> 4;
  const int m0   = blockIdx.x*64;
  const int n0   = wv*64;
  const int nt0  = n0 >> 4;     // 4 ntiles per wave

  f32x4 acc[4][4];
  #pragma unroll
  for(int i=0;i<4;i++)
    #pragma unroll
    for(int j=0;j<4;j++){ acc[i][j][0]=0.f; acc[i][j][1]=0.f; acc[i][j][2]=0.f; acc[i][j][3]=0.f; }

  #pragma unroll
  for(int t=0; t<8; t++){
    short8 a_h[4], a_l[4], b_h[4], b_l[4];
    #pragma unroll
    for(int i=0;i<4;i++){
      size_t ad = ((size_t)t*Mpad + (m0 + i*16 + l15))*32 + quad*8;
      a_h[i] = *(const short8*)&Ah[ad];
      a_l[i] = *(const short8*)&Al[ad];
    }
    #pragma unroll
    for(int j=0;j<4;j++){
      if(nt0 + j < ntiles){
        size_t bd = (((size_t)(nt0+j)*8 + t)*64 + lane)*8;
        b_h[j] = *(const short8*)&Bh[bd];
        b_l[j] = *(const short8*)&Bl[bd];
      }
    }
    #pragma unroll
    for(int i=0;i<4;i++)
      #pragma unroll
      for(int j=0;j<4;j++){
        if(nt0 + j < ntiles){
          acc[i][j] = __builtin_amdgcn_mfma_f32_16x16x32_bf16(a_h[i], b_h[j], acc[i][j], 0,0,0);
          acc[i][j] = __builtin_amdgcn_mfma_f32_16x16x32_bf16(a_h[i], b_l[j], acc[i][j], 0,0,0);
          acc[i][j] = __builtin_amdgcn_mfma_f32_16x16x32_bf16(a_l[i], b_h[j], acc[i][j], 0,0,0);
        }
      }
  }

  // fused el/er (layers 0/1): this wave's col-tile is exactly head wv
  if(al){
    const int h = wv;
    float alv[4], arv[4];
    #pragma unroll
    for(int j=0;j<4;j++){
      alv[j] = al[h*64 + j*16 + l15];
      arv[j] = ar[h*64 + j*16 + l15];
    }
    #pragma unroll
    for(int i=0;i<4;i++){
      #pragma unroll
      for(int r=0;r<4;r++){
        float pl = acc[i][0][r]*alv[0] + acc[i][1][r]*alv[1]
                 + acc[i][2][r]*alv[2] + acc[i][3][r]*alv[3];
        float pr = acc[i][0][r]*arv[0] + acc[i][1][r]*arv[1]
                 + acc[i][2][r]*arv[2] + acc[i][3][r]*arv[3];
        #pragma unroll
        for(int off=1; off<16; off<<=1){ pl += __shfl_xor(pl,off); pr += __shfl_xor(pr,off); }
        int gm = m0 + i*16 + quad*4 + r;
        if(l15==0 && gm < M){ el[gm*4+h] = pl; er[gm*4+h] = pr; }
      }
    }
  }

  // C store, row-major bf16.  C/D layout: col=lane&15, row=quad*4+r
  #pragma unroll
  for(int i=0;i<4;i++){
    #pragma unroll
    for(int r=0;r<4;r++){
      int gm = m0 + i*16 + quad*4 + r;
      if(gm >= M) continue;
      #pragma unroll
      for(int j=0;j<4;j++){
        int gn = n0 + j*16 + l15;
        if(gn < N) Cm[(size_t)gm*N + gn] = f2bf(acc[i][j][r]);
      }
    }
  }
}

// ---------------- el/er projection from bf16 feat (layer 2 only) ----------------
__global__ void attn_proj_bf(const __hip_bfloat16* __restrict__ feat, const float* __restrict__ a_l,
                             const float* __restrict__ a_r, float* __restrict__ el,
                             float* __restrict__ er, int D){
  int n = blockIdx.x;
  int h = threadIdx.x >> 6;
  int lane = threadIdx.x & 63;
  float vl = 0.f, vr = 0.f;
  for(int d=lane; d<D; d+=64){
    float f = (float)feat[(size_t)n*4*D + h*D + d];
    vl = fmaf(f, a_l[h*D+d], vl);
    vr = fmaf(f, a_r[h*D+d], vr);
  }
  #pragma unroll
  for(int off=32; off; off>>=1){ vl += __shfl_down(vl,off); vr += __shfl_down(vr,off); }
  if(lane==0){ el[n*4+h] = vl; er[n*4+h] = vr; }
}

// ---------------- softmax + aggregate, layers 0/1 (H*D=256 bf16), ELU ----------------
// Edge-weight computation FUSED: w = exp(leaky(el[s]+er[n])); el table 800KB, L2-resident.
// One WAVE per dst node; 2 edge-slots x 32 dim-lanes (16B uint4 per lane = 8 dims).
// Settled r1-r3: at compulsory-miss floor (~200MB fetch, ~3.9 TB/s) — do not touch.
__global__ __launch_bounds__(256) void agg_kernel(const uint4* __restrict__ feat4,
                           const float* __restrict__ el, const float* __restrict__ er,
                           const int* __restrict__ offsets, const int* __restrict__ ssrc,
                           const float* __restrict__ bias,
                           ushortT* __restrict__ Hh, ushortT* __restrict__ Hl,
                           int N, int Mpad){
  int wvi  = threadIdx.x >> 6;
  int lane = threadIdx.x & 63;
  int n = blockIdx.x*4 + wvi;
  if(n >= N) return;
  const int slot = lane >> 5;          // edge slot 0/1
  const int wl   = lane & 31;          // dim-lane: owns dims wl*8..wl*8+7
  const int head = wl >> 3;            // 8 lanes per head (64 dims / 8 per lane)
  const float ern = er[n*4 + head];    // wave-constant per lane
  int e0 = offsets[n], e1 = offsets[n+1];
  float a0=0.f,a1=0.f,a2=0.f,a3=0.f,a4=0.f,a5=0.f,a6=0.f,a7=0.f;
  float den = 0.f;
  int e = e0;
  for(; e+7 < e1; e += 8){
    int4u sv = *(const int4u*)&ssrc[e + slot*4];
    #pragma unroll
    for(int i=0;i<4;i++){
      int s = sv[i];
      float w = __expf(leaky(el[s*4 + head] + ern));
      uint4 q = feat4[(size_t)s*32 + wl];
      a0 = fmaf(w, bf_lo(q.x), a0); a1 = fmaf(w, bf_hi(q.x), a1);
      a2 = fmaf(w, bf_lo(q.y), a2); a3 = fmaf(w, bf_hi(q.y), a3);
      a4 = fmaf(w, bf_lo(q.z), a4); a5 = fmaf(w, bf_hi(q.z), a5);
      a6 = fmaf(w, bf_lo(q.w), a6); a7 = fmaf(w, bf_hi(q.w), a7);
      den += w;
    }
  }
  for(; e < e1; e += 2){              // tail: <=4 iterations (remainder <8)
    int ee = e + slot;
    int ec = (ee < e1) ? ee : (e1 - 1);     // clamp: safe row, weight zeroed
    int s = ssrc[ec];
    float w = (ee < e1) ? __expf(leaky(el[s*4 + head] + ern)) : 0.f;
    uint4 q = feat4[(size_t)s*32 + wl];
    a0 = fmaf(w, bf_lo(q.x), a0); a1 = fmaf(w, bf_hi(q.x), a1);
    a2 = fmaf(w, bf_lo(q.y), a2); a3 = fmaf(w, bf_hi(q.y), a3);
    a4 = fmaf(w, bf_lo(q.z), a4); a5 = fmaf(w, bf_hi(q.z), a5);
    a6 = fmaf(w, bf_lo(q.w), a6); a7 = fmaf(w, bf_hi(q.w), a7);
    den += w;
  }
  // combine the two edge slots
  a0 += __shfl_xor(a0,32); a1 += __shfl_xor(a1,32);
  a2 += __shfl_xor(a2,32); a3 += __shfl_xor(a3,32);
  a4 += __shfl_xor(a4,32); a5 += __shfl_xor(a5,32);
  a6 += __shfl_xor(a6,32); a7 += __shfl_xor(a7,32);
  den += __shfl_xor(den,32);
  if(slot == 0){
    float inv = 1.f / fmaxf(den, 1e-9f);
    int k0 = wl*8;
    float4 b4a = *(const float4*)&bias[k0];
    float4 b4b = *(const float4*)&bias[k0+4];
    float o[8];
    o[0] = elu(a0*inv + b4a.x); o[1] = elu(a1*inv + b4a.y);
    o[2] = elu(a2*inv + b4a.z); o[3] = elu(a3*inv + b4a.w);
    o[4] = elu(a4*inv + b4b.x); o[5] = elu(a5*inv + b4b.y);
    o[6] = elu(a6*inv + b4b.z); o[7] = elu(a7*inv + b4b.w);
    ushortT hh[8], ll[8];
    #pragma unroll
    for(int j=0;j<8;j++){
      hh[j] = f2bf(o[j]);
      ll[j] = f2bf(o[j] - bf2f(hh[j]));
    }
    // A-plane store: dims k0..k0+7 -> t=k0/32, chunk offset k0%32 (16B-aligned)
    int t  = wl >> 2;
    int co = (wl & 3) * 8;
    size_t ad = ((size_t)t*Mpad + n)*32 + co;
    *(short8*)&Hh[ad] = *(short8*)hh;
    *(short8*)&Hl[ad] = *(short8*)ll;
  }
}

// ---------------- layer 2: aggregate (H*C=160 bf16) + head-mean logits ----------------
// 3 edge-slots x 20 dim-lanes (16B uint4 = 8 bf16 dims each; 320B row = 20 lanes).
__global__ __launch_bounds__(256) void agg2_kernel(const uint4* __restrict__ feat4,
                            const float* __restrict__ el, const float* __restrict__ er,
                            const int* __restrict__ offsets, const int* __restrict__ ssrc,
                            const float* __restrict__ bias, float* __restrict__ logits,
                            int N){
  int wv = threadIdx.x >> 6;
  int lane = threadIdx.x & 63;
  int n = blockIdx.x*4 + wv;
  if(n >= N) return;
  const int slot = lane / 20;          // 0,1,2 active; slot 3 (lanes 60-63) w=0
  const int wl   = lane - slot*20;     // dim-lane: owns dims wl*8..wl*8+7
  const int head = wl / 5;             // 5 lanes per head (40 dims = 80B)
  const float ern = er[n*4 + head];
  int e0 = offsets[n], e1 = offsets[n+1];
  float a0=0.f,a1=0.f,a2=0.f,a3=0.f,a4=0.f,a5=0.f,a6=0.f,a7=0.f;
  float den = 0.f;
  #pragma unroll 2
  for(int e = e0; e < e1; e += 3){
    int ee = e + ((slot < 3) ? slot : 2);
    int ec = (ee < e1) ? ee : (e1 - 1);       // clamped safe index
    int s = ssrc[ec];
    bool act = (slot < 3) && (ee < e1);
    float w = act ? __expf(leaky(el[s*4 + head] + ern)) : 0.f;
    uint4 q = feat4[(size_t)s*20 + wl];
    a0 = fmaf(w, bf_lo(q.x), a0); a1 = fmaf(w, bf_hi(q.x), a1);
    a2 = fmaf(w, bf_lo(q.y), a2); a3 = fmaf(w, bf_hi(q.y), a3);
    a4 = fmaf(w, bf_lo(q.z), a4); a5 = fmaf(w, bf_hi(q.z), a5);
    a6 = fmaf(w, bf_lo(q.w), a6); a7 = fmaf(w, bf_hi(q.w), a7);
    den += w;
  }
  // slot-reduce: lane += lane+20, lane+40 (results valid on lanes 0-19)
  {
    float t1, t2;
    t1 = __shfl(a0, lane+20); t2 = __shfl(a0, lane+40); a0 += t1 + t2;
    t1 = __shfl(a1, lane+20); t2 = __shfl(a1, lane+40); a1 += t1 + t2;
    t1 = __shfl(a2, lane+20); t2 = __shfl(a2, lane+40); a2 += t1 + t2;
    t1 = __shfl(a3, lane+20); t2 = __shfl(a3, lane+40); a3 += t1 + t2;
    t1 = __shfl(a4, lane+20); t2 = __shfl(a4, lane+40); a4 += t1 + t2;
    t1 = __shfl(a5, lane+20); t2 = __shfl(a5, lane+40); a5 += t1 + t2;
    t1 = __shfl(a6, lane+20); t2 = __shfl(a6, lane+40); a6 += t1 + t2;
    t1 = __shfl(a7, lane+20); t2 = __shfl(a7, lane+40); a7 += t1 + t2;
    t1 = __shfl(den, lane+20); t2 = __shfl(den, lane+40); den += t1 + t2;
  }
  if(slot == 0){                       // lanes 0-19
    float inv = 1.f / fmaxf(den, 1e-9f);
    float4 ba = *(const float4*)&bias[wl*8];
    float4 bb = *(const float4*)&bias[wl*8+4];
    float o[8];
    o[0] = a0*inv + ba.x; o[1] = a1*inv + ba.y; o[2] = a2*inv + ba.z; o[3] = a3*inv + ba.w;
    o[4] = a4*inv + bb.x; o[5] = a5*inv + bb.y; o[6] = a6*inv + bb.z; o[7] = a7*inv + bb.w;
    // head-mean: class c lives on lanes {c/8 + 5h}; tree: +5 then +10
    #pragma unroll
    for(int j=0;j<8;j++){
      float t = __shfl(o[j], lane+5);  o[j] += t;
      t       = __shfl(o[j], lane+10); o[j] += t;
    }
    if(wl < 5){
      float4 r0, r1;
      r0.x = 0.25f*o[0]; r0.y = 0.25f*o[1]; r0.z = 0.25f*o[2]; r0.w = 0.25f*o[3];
      r1.x = 0.25f*o[4]; r1.y = 0.25f*o[5]; r1.z = 0.25f*o[6]; r1.w = 0.25f*o[7];
      *(float4*)&logits[(size_t)n*40 + wl*8]     = r0;
      *(float4*)&logits[(size_t)n*40 + wl*8 + 4] = r1;
    }
  }
}

extern "C" void kernel_launch(void* const* d_in, const int* in_sizes, int n_in,
                              void* d_out, int out_size, void* d_ws, size_t ws_size,
                              hipStream_t stream){
  const float* x   = (const float*)d_in[0];
  const int*   eix = (const int*)  d_in[1];
  const float* W0  = (const float*)d_in[2];
  const float* al0 = (const float*)d_in[3];
  const float* ar0 = (const float*)d_in[4];
  const float* b0  = (const float*)d_in[5];
  const float* W1  = (const float*)d_in[6];
  const float* al1 = (const float*)d_in[7];
  const float* ar1 = (const float*)d_in[8];
  const float* b1  = (const float*)d_in[9];
  const float* W2  = (const float*)d_in[10];
  const float* al2 = (const float*)d_in[11];
  const float* ar2 = (const float*)d_in[12];
  const float* b2  = (const float*)d_in[13];
  float* logits = (float*)d_out;

  const int N = in_sizes[0] / 256;   // 50000
  const int E = in_sizes[1] / 2;     // 800000
  const int* src = eix;
  const int* dst = eix + E;
  const int nb = (N + 1023) / 1024;

  char* ws = (char*)d_ws;
  auto alloc = [&](size_t bytes)->char*{
    char* p = ws; ws += (bytes + 255) & ~(size_t)255; return p;
  };
  const int nblocksM = (N + 127)/128;
  const int Mpad = nblocksM * 128;
  const size_t apackElems = (size_t)Mpad * 256;
  int*   counts    = (int*)  alloc((size_t)N*4);
  int*   offsets   = (int*)  alloc((size_t)(N+1)*4);
  int*   cursor    = (int*)  alloc((size_t)N*4);
  int*   blocksums = (int*)  alloc((size_t)nb*4);
  int*   ssrc      = (int*)  alloc((size_t)E*4);
  __hip_bfloat16* bufF = (__hip_bfloat16*)alloc((size_t)N*256*2);   // gemm output (bf16, row-major)
  ushortT* Hh      = (ushortT*)alloc(apackElems*2);                  // A hi plane [t][Mpad][32]
  ushortT* Hl      = (ushortT*)alloc(apackElems*2);                  // A lo plane
  float* el_buf    = (float*)alloc((size_t)N*4*4);
  float* er_buf    = (float*)alloc((size_t)N*4*4);
  ushortT* Wph0 = (ushortT*)alloc(16*8*64*8*2);
  ushortT* Wpl0 = (ushortT*)alloc(16*8*64*8*2);
  ushortT* Wph1 = (ushortT*)alloc(16*8*64*8*2);
  ushortT* Wpl1 = (ushortT*)alloc(16*8*64*8*2);
  ushortT* Wph2 = (ushortT*)alloc(16*8*64*8*2);
  ushortT* Wpl2 = (ushortT*)alloc(16*8*64*8*2);

  // sort edges by dst (graph fixed across layers — one sort per call)
  hipMemsetAsync(counts, 0, (size_t)N*4, stream);
  hist_kernel   <<<(E+255)/256, 256, 0, stream>>>(dst, E, counts);
  scan1_kernel  <<<nb, 1024, 0, stream>>>(counts, N, offsets, blocksums);
  scan3_kernel  <<<nb, 1024, 0, stream>>>(offsets, blocksums, N, E, cursor);
  scatter_kernel<<<(E+255)/256, 256, 0, stream>>>(src, dst, E, cursor, ssrc);

  // fused packing: x-split + 3x W-split in ONE dispatch
  int xblocks = (8*Mpad + 255)/256;
  pack_all<<<xblocks + 96, 256, 0, stream>>>(x, N, Mpad, xblocks, Hh, Hl,
                                             W0, W1, W2, Wph0, Wpl0, Wph1, Wpl1, Wph2, Wpl2);

  int ggBlocks = Mpad / 64;        // block = 64 rows x full-N
  int aggGrid  = (N+3)/4;
  // layer 0 (el/er fused in gemm epilogue; edge weights fused in agg)
  gemm_packed<<<ggBlocks, 256, 0, stream>>>(Hh, Hl, Wph0, Wpl0, (ushortT*)bufF, N, Mpad, 256, 16, al0, ar0, el_buf, er_buf);
  agg_kernel<<<aggGrid, 256, 0, stream>>>((const uint4*)bufF, el_buf, er_buf, offsets, ssrc, b0, Hh, Hl, N, Mpad);
  // layer 1
  gemm_packed<<<ggBlocks, 256, 0, stream>>>(Hh, Hl, Wph1, Wpl1, (ushortT*)bufF, N, Mpad, 256, 16, al1, ar1, el_buf, er_buf);
  agg_kernel<<<aggGrid, 256, 0, stream>>>((const uint4*)bufF, el_buf, er_buf, offsets, ssrc, b1, Hh, Hl, N, Mpad);
  // layer 2 (ntiles=10: waves 2/3 skip B-loads+MFMA beyond col 160)
  gemm_packed<<<ggBlocks, 256, 0, stream>>>(Hh, Hl, Wph2, Wpl2, (ushortT*)bufF, N, Mpad, 160, 10, nullptr, nullptr, nullptr, nullptr);
  attn_proj_bf<<<N, 256, 0, stream>>>(bufF, al2, ar2, el_buf, er_buf, 40);
  agg2_kernel<<<aggGrid, 256, 0, stream>>>((const uint4*)bufF, el_buf, er_buf, offsets, ssrc, b2, logits, N);
}

// Round 6
// 510.764 us; speedup vs baseline: 1.0837x; 1.0837x over previous
//
#include <hip/hip_runtime.h>
#include <hip/hip_bf16.h>
#include <math.h>

#define NEG_SLOPE 0.2f

typedef unsigned short ushortT;
typedef __attribute__((ext_vector_type(8))) short short8;   // 8 bf16 = 4 VGPRs (MFMA A/B frag)
typedef __attribute__((ext_vector_type(4))) float f32x4;    // MFMA C/D frag
typedef __attribute__((ext_vector_type(4), aligned(4))) int   int4u;   // 4B-aligned int4 load

static __device__ __forceinline__ float leaky(float x){ return x > 0.f ? x : NEG_SLOPE * x; }
static __device__ __forceinline__ float elu(float x){ return x > 0.f ? x : (__expf(x) - 1.f); }

// bf16 helpers: RNE pack, exact unpack
static __device__ __forceinline__ ushortT f2bf(float f){
  unsigned u = __float_as_uint(f);
  u += 0x7fff + ((u >> 16) & 1);
  return (ushortT)(u >> 16);
}
static __device__ __forceinline__ float bf2f(ushortT h){ return __uint_as_float((unsigned)h << 16); }
static __device__ __forceinline__ float bf_lo(unsigned u){ return __uint_as_float(u << 16); }
static __device__ __forceinline__ float bf_hi(unsigned u){ return __uint_as_float(u & 0xffff0000u); }

// A-plane layout: elem (row,k) -> [ (k/32)*Mpad + row ]*32 + k%32
// B-plane layout: [(ntile*8 + t)*64 + lane]*8 (contiguous 1KB per wave frag)

// ---------------- edge sort by dst (counting sort) ----------------
__global__ void hist_kernel(const int* __restrict__ dst, int E, int* __restrict__ counts){
  int i = blockIdx.x*blockDim.x + threadIdx.x;
  if(i < E) atomicAdd(&counts[dst[i]], 1);
}

__global__ void scan1_kernel(const int* __restrict__ counts, int N,
                             int* __restrict__ offsets, int* __restrict__ blocksums){
  __shared__ int sdata[1024];
  int i = blockIdx.x*1024 + threadIdx.x;
  int v = (i<N) ? counts[i] : 0;
  sdata[threadIdx.x] = v;
  __syncthreads();
  for(int off=1; off<1024; off<<=1){
    int t = (threadIdx.x >= off) ? sdata[threadIdx.x-off] : 0;
    __syncthreads();
    sdata[threadIdx.x] += t;
    __syncthreads();
  }
  if(i<N) offsets[i] = sdata[threadIdx.x] - v;
  if(threadIdx.x==1023) blocksums[blockIdx.x] = sdata[1023];
}

// scan2 folded in: each block serially sums blocksums[0..blockIdx) (<=48 ints, L2-hot)
__global__ void scan3_kernel(int* __restrict__ offsets, const int* __restrict__ blocksums,
                             int N, int E, int* __restrict__ cursor){
  __shared__ int sbase;
  if(threadIdx.x == 0){
    int s = 0;
    for(int i=0;i<(int)blockIdx.x;i++) s += blocksums[i];
    sbase = s;
  }
  __syncthreads();
  int i = blockIdx.x*1024 + threadIdx.x;
  if(i < N){
    int o = offsets[i] + sbase;
    offsets[i] = o;
    cursor[i] = o;
  }
  if(i == 0) offsets[N] = E;
}

__global__ void scatter_kernel(const int* __restrict__ src, const int* __restrict__ dst, int E,
                               int* __restrict__ cursor, int* __restrict__ ssrc){
  int i = blockIdx.x*blockDim.x + threadIdx.x;
  if(i < E){
    int d = dst[i];
    int p = atomicAdd(&cursor[d], 1);
    ssrc[p] = src[i];
  }
}

// ---------------- fused packing: xsplit (blocks [0,xblocks)) + 3x wsplit (next 96) ----------------
__global__ __launch_bounds__(256) void pack_all(
    const float* __restrict__ x, int M, int Mpad, int xblocks,
    ushortT* __restrict__ Xh, ushortT* __restrict__ Xl,
    const float* __restrict__ W0, const float* __restrict__ W1, const float* __restrict__ W2,
    ushortT* __restrict__ Wph0, ushortT* __restrict__ Wpl0,
    ushortT* __restrict__ Wph1, ushortT* __restrict__ Wpl1,
    ushortT* __restrict__ Wph2, ushortT* __restrict__ Wpl2){
  int b = blockIdx.x;
  if(b < xblocks){
    // ---- x split fp32 [M][256] -> A-plane layout [t][Mpad][32] ----
    int idx = b*256 + threadIdx.x;
    if(idx >= 8*Mpad) return;
    int t = idx / Mpad, m = idx - t*Mpad;
    size_t base = (size_t)idx * 32;
    if(m < M){
      const float* xr = &x[(size_t)m*256 + t*32];
      #pragma unroll
      for(int c=0;c<4;c++){
        float4 v0 = *(const float4*)&xr[c*8];
        float4 v1 = *(const float4*)&xr[c*8+4];
        float vv[8] = {v0.x,v0.y,v0.z,v0.w,v1.x,v1.y,v1.z,v1.w};
        ushortT h[8], l[8];
        #pragma unroll
        for(int j=0;j<8;j++){
          h[j] = f2bf(vv[j]);
          l[j] = f2bf(vv[j] - bf2f(h[j]));
        }
        *(short8*)&Xh[base + c*8] = *(short8*)h;
        *(short8*)&Xl[base + c*8] = *(short8*)l;
      }
    } else {
      short8 z = {0,0,0,0,0,0,0,0};
      #pragma unroll
      for(int c=0;c<4;c++){ *(short8*)&Xh[base + c*8] = z; *(short8*)&Xl[base + c*8] = z; }
    }
  } else {
    // ---- W split: W[K=256, N] -> packed fragment order [16 ntiles] ----
    int wb = b - xblocks;            // 0..95
    int which = wb >> 5;             // 0,1,2
    const float* W = (which==0) ? W0 : (which==1) ? W1 : W2;
    ushortT* Wh = (which==0) ? Wph0 : (which==1) ? Wph1 : Wph2;
    ushortT* Wl = (which==0) ? Wpl0 : (which==1) ? Wpl1 : Wpl2;
    int Nn = (which==2) ? 160 : 256;
    int idx = (wb & 31)*256 + threadIdx.x;   // < 8192
    int lane = idx & 63;
    int t  = (idx >> 6) & 7;
    int nt = idx >> 9;
    int l15 = lane & 15, quad = lane >> 4;
    int n = nt*16 + l15;
    ushortT h[8], l[8];
    #pragma unroll
    for(int j=0;j<8;j++){
      int k = t*32 + quad*8 + j;
      float v = (n < Nn) ? W[(size_t)k*Nn + n] : 0.f;
      h[j] = f2bf(v);
      l[j] = f2bf(v - bf2f(h[j]));
    }
    *(short8*)&Wh[(size_t)idx*8] = *(short8*)h;
    *(short8*)&Wl[(size_t)idx*8] = *(short8*)l;
  }
}

// ---------------- bf16x3 MFMA GEMM with LDS-staged A-tile ----------------
// Block = 32 rows x full N, 4 waves side-by-side in N. The A-tile (32 rows x 256 k x
// hi/lo = 32KB) is staged to LDS ONCE per block with a fully-coalesced copy (rows are
// contiguous per t in the A-plane layout), then fragments come from ds_read_b128
// (~12cy) instead of 4x-redundant per-wave global loads (~200cy) — removes the
// latency chain that made the no-LDS version ~3x slower than its roofline.
// B (L2-resident, 256KB) stays direct; full unroll lets the compiler hoist t+1 loads.
__global__ __launch_bounds__(256) void gemm_packed(
    const ushortT* __restrict__ Ah, const ushortT* __restrict__ Al,
    const ushortT* __restrict__ Bh, const ushortT* __restrict__ Bl,
    ushortT* __restrict__ Cm, int M, int Mpad, int N, int ntiles,
    const float* __restrict__ al, const float* __restrict__ ar,
    float* __restrict__ el, float* __restrict__ er){
  __shared__ ushortT sAh[8192];   // [t][32 rows][32 k]  = 16KB
  __shared__ ushortT sAl[8192];   // 16KB
  const int tid  = threadIdx.x;
  const int lane = tid & 63;
  const int wv   = tid >> 6;
  const int l15  = lane & 15, quad = lane >> 4;
  const int m0   = blockIdx.x*32;
  const int n0   = wv*64;
  const int nt0  = n0 >> 4;     // 4 ntiles per wave

  // stage A-tile: short8-chunk c -> t = c>>7, rem = c&127 (= r*4 + kchunk);
  // global short8 idx = (t*Mpad + m0)*4 + rem  (rows contiguous per t-plane)
  {
    const short8* gh = (const short8*)Ah;
    const short8* gl = (const short8*)Al;
    short8* sh = (short8*)sAh;
    short8* sl = (short8*)sAl;
    #pragma unroll
    for(int c0=0;c0<4;c0++){
      int c = c0*256 + tid;               // 0..1023
      int t = c >> 7;
      int rem = c & 127;
      size_t g = ((size_t)t*Mpad + m0)*4 + rem;
      sh[c] = gh[g];
      sl[c] = gl[g];
    }
  }
  __syncthreads();

  f32x4 acc[2][4];
  #pragma unroll
  for(int i=0;i<2;i++)
    #pragma unroll
    for(int j=0;j<4;j++){ acc[i][j][0]=0.f; acc[i][j][1]=0.f; acc[i][j][2]=0.f; acc[i][j][3]=0.f; }

  const short8* sh8 = (const short8*)sAh;
  const short8* sl8 = (const short8*)sAl;
  const short8* bh8 = (const short8*)Bh;
  const short8* bl8 = (const short8*)Bl;

  #pragma unroll
  for(int t=0; t<8; t++){
    short8 a_h[2], a_l[2], b_h[4], b_l[4];
    #pragma unroll
    for(int i=0;i<2;i++){
      int ci = t*128 + (i*16 + l15)*4 + quad;   // short8 units
      a_h[i] = sh8[ci];
      a_l[i] = sl8[ci];
    }
    #pragma unroll
    for(int j=0;j<4;j++){
      if(nt0 + j < ntiles){
        size_t bd = (((size_t)(nt0+j)*8 + t)*64 + lane);   // short8 units
        b_h[j] = bh8[bd];
        b_l[j] = bl8[bd];
      }
    }
    #pragma unroll
    for(int i=0;i<2;i++)
      #pragma unroll
      for(int j=0;j<4;j++){
        if(nt0 + j < ntiles){
          acc[i][j] = __builtin_amdgcn_mfma_f32_16x16x32_bf16(a_h[i], b_h[j], acc[i][j], 0,0,0);
          acc[i][j] = __builtin_amdgcn_mfma_f32_16x16x32_bf16(a_h[i], b_l[j], acc[i][j], 0,0,0);
          acc[i][j] = __builtin_amdgcn_mfma_f32_16x16x32_bf16(a_l[i], b_h[j], acc[i][j], 0,0,0);
        }
      }
  }

  // fused el/er (layers 0/1): this wave's col-tile is exactly head wv
  if(al){
    const int h = wv;
    float alv[4], arv[4];
    #pragma unroll
    for(int j=0;j<4;j++){
      alv[j] = al[h*64 + j*16 + l15];
      arv[j] = ar[h*64 + j*16 + l15];
    }
    #pragma unroll
    for(int i=0;i<2;i++){
      #pragma unroll
      for(int r=0;r<4;r++){
        float pl = acc[i][0][r]*alv[0] + acc[i][1][r]*alv[1]
                 + acc[i][2][r]*alv[2] + acc[i][3][r]*alv[3];
        float pr = acc[i][0][r]*arv[0] + acc[i][1][r]*arv[1]
                 + acc[i][2][r]*arv[2] + acc[i][3][r]*arv[3];
        #pragma unroll
        for(int off=1; off<16; off<<=1){ pl += __shfl_xor(pl,off); pr += __shfl_xor(pr,off); }
        int gm = m0 + i*16 + quad*4 + r;
        if(l15==0 && gm < M){ el[gm*4+h] = pl; er[gm*4+h] = pr; }
      }
    }
  }

  // C store, row-major bf16.  C/D layout: col=lane&15, row=quad*4+r
  #pragma unroll
  for(int i=0;i<2;i++){
    #pragma unroll
    for(int r=0;r<4;r++){
      int gm = m0 + i*16 + quad*4 + r;
      if(gm >= M) continue;
      #pragma unroll
      for(int j=0;j<4;j++){
        int gn = n0 + j*16 + l15;
        if(gn < N) Cm[(size_t)gm*N + gn] = f2bf(acc[i][j][r]);
      }
    }
  }
}

// ---------------- el/er projection from bf16 feat (layer 2 only) ----------------
// 4 nodes/block (one wave per node), 16 lanes per head, vectorized 4B loads:
// lane c covers dims {2c,2c+1} and (c<4) {32+2c,33+2c} of the head's 40 dims.
__global__ __launch_bounds__(256) void attn_proj_bf(const ushortT* __restrict__ feat,
                             const float* __restrict__ a_l, const float* __restrict__ a_r,
                             float* __restrict__ el, float* __restrict__ er, int N){
  int wv = threadIdx.x >> 6;
  int lane = threadIdx.x & 63;
  int n = blockIdx.x*4 + wv;
  if(n >= N) return;
  int h = lane >> 4, c = lane & 15;
  const unsigned* row = (const unsigned*)&feat[((size_t)n*4 + h)*40];
  const float2* alp = (const float2*)&a_l[h*40];
  const float2* arp = (const float2*)&a_r[h*40];
  unsigned u0 = row[c];
  float2 al0 = alp[c], ar0 = arp[c];
  float f0 = bf_lo(u0), f1 = bf_hi(u0);
  float vl = f0*al0.x + f1*al0.y;
  float vr = f0*ar0.x + f1*ar0.y;
  if(c < 4){
    unsigned u1 = row[16 + c];
    float2 al1 = alp[16 + c], ar1 = arp[16 + c];
    float g0 = bf_lo(u1), g1 = bf_hi(u1);
    vl += g0*al1.x + g1*al1.y;
    vr += g0*ar1.x + g1*ar1.y;
  }
  #pragma unroll
  for(int off=1; off<16; off<<=1){ vl += __shfl_xor(vl, off); vr += __shfl_xor(vr, off); }
  if(c == 0){ el[n*4+h] = vl; er[n*4+h] = vr; }
}

// ---------------- softmax + aggregate, layers 0/1 (H*D=256 bf16), ELU ----------------
// Settled r1-r3: at compulsory-miss floor (~200MB fetch, ~3.9 TB/s) — do not touch.
__global__ __launch_bounds__(256) void agg_kernel(const uint4* __restrict__ feat4,
                           const float* __restrict__ el, const float* __restrict__ er,
                           const int* __restrict__ offsets, const int* __restrict__ ssrc,
                           const float* __restrict__ bias,
                           ushortT* __restrict__ Hh, ushortT* __restrict__ Hl,
                           int N, int Mpad){
  int wvi  = threadIdx.x >> 6;
  int lane = threadIdx.x & 63;
  int n = blockIdx.x*4 + wvi;
  if(n >= N) return;
  const int slot = lane >> 5;          // edge slot 0/1
  const int wl   = lane & 31;          // dim-lane: owns dims wl*8..wl*8+7
  const int head = wl >> 3;            // 8 lanes per head (64 dims / 8 per lane)
  const float ern = er[n*4 + head];    // wave-constant per lane
  int e0 = offsets[n], e1 = offsets[n+1];
  float a0=0.f,a1=0.f,a2=0.f,a3=0.f,a4=0.f,a5=0.f,a6=0.f,a7=0.f;
  float den = 0.f;
  int e = e0;
  for(; e+7 < e1; e += 8){
    int4u sv = *(const int4u*)&ssrc[e + slot*4];
    #pragma unroll
    for(int i=0;i<4;i++){
      int s = sv[i];
      float w = __expf(leaky(el[s*4 + head] + ern));
      uint4 q = feat4[(size_t)s*32 + wl];
      a0 = fmaf(w, bf_lo(q.x), a0); a1 = fmaf(w, bf_hi(q.x), a1);
      a2 = fmaf(w, bf_lo(q.y), a2); a3 = fmaf(w, bf_hi(q.y), a3);
      a4 = fmaf(w, bf_lo(q.z), a4); a5 = fmaf(w, bf_hi(q.z), a5);
      a6 = fmaf(w, bf_lo(q.w), a6); a7 = fmaf(w, bf_hi(q.w), a7);
      den += w;
    }
  }
  for(; e < e1; e += 2){              // tail: <=4 iterations (remainder <8)
    int ee = e + slot;
    int ec = (ee < e1) ? ee : (e1 - 1);     // clamp: safe row, weight zeroed
    int s = ssrc[ec];
    float w = (ee < e1) ? __expf(leaky(el[s*4 + head] + ern)) : 0.f;
    uint4 q = feat4[(size_t)s*32 + wl];
    a0 = fmaf(w, bf_lo(q.x), a0); a1 = fmaf(w, bf_hi(q.x), a1);
    a2 = fmaf(w, bf_lo(q.y), a2); a3 = fmaf(w, bf_hi(q.y), a3);
    a4 = fmaf(w, bf_lo(q.z), a4); a5 = fmaf(w, bf_hi(q.z), a5);
    a6 = fmaf(w, bf_lo(q.w), a6); a7 = fmaf(w, bf_hi(q.w), a7);
    den += w;
  }
  // combine the two edge slots
  a0 += __shfl_xor(a0,32); a1 += __shfl_xor(a1,32);
  a2 += __shfl_xor(a2,32); a3 += __shfl_xor(a3,32);
  a4 += __shfl_xor(a4,32); a5 += __shfl_xor(a5,32);
  a6 += __shfl_xor(a6,32); a7 += __shfl_xor(a7,32);
  den += __shfl_xor(den,32);
  if(slot == 0){
    float inv = 1.f / fmaxf(den, 1e-9f);
    int k0 = wl*8;
    float4 b4a = *(const float4*)&bias[k0];
    float4 b4b = *(const float4*)&bias[k0+4];
    float o[8];
    o[0] = elu(a0*inv + b4a.x); o[1] = elu(a1*inv + b4a.y);
    o[2] = elu(a2*inv + b4a.z); o[3] = elu(a3*inv + b4a.w);
    o[4] = elu(a4*inv + b4b.x); o[5] = elu(a5*inv + b4b.y);
    o[6] = elu(a6*inv + b4b.z); o[7] = elu(a7*inv + b4b.w);
    ushortT hh[8], ll[8];
    #pragma unroll
    for(int j=0;j<8;j++){
      hh[j] = f2bf(o[j]);
      ll[j] = f2bf(o[j] - bf2f(hh[j]));
    }
    // A-plane store: dims k0..k0+7 -> t=k0/32, chunk offset k0%32 (16B-aligned)
    int t  = wl >> 2;
    int co = (wl & 3) * 8;
    size_t ad = ((size_t)t*Mpad + n)*32 + co;
    *(short8*)&Hh[ad] = *(short8*)hh;
    *(short8*)&Hl[ad] = *(short8*)ll;
  }
}

// ---------------- layer 2: aggregate (H*C=160 bf16) + head-mean logits ----------------
// 3 edge-slots x 20 dim-lanes (16B uint4 = 8 bf16 dims each; 320B row = 20 lanes).
__global__ __launch_bounds__(256) void agg2_kernel(const uint4* __restrict__ feat4,
                            const float* __restrict__ el, const float* __restrict__ er,
                            const int* __restrict__ offsets, const int* __restrict__ ssrc,
                            const float* __restrict__ bias, float* __restrict__ logits,
                            int N){
  int wv = threadIdx.x >> 6;
  int lane = threadIdx.x & 63;
  int n = blockIdx.x*4 + wv;
  if(n >= N) return;
  const int slot = lane / 20;          // 0,1,2 active; slot 3 (lanes 60-63) w=0
  const int wl   = lane - slot*20;     // dim-lane: owns dims wl*8..wl*8+7
  const int head = wl / 5;             // 5 lanes per head (40 dims = 80B)
  const float ern = er[n*4 + head];
  int e0 = offsets[n], e1 = offsets[n+1];
  float a0=0.f,a1=0.f,a2=0.f,a3=0.f,a4=0.f,a5=0.f,a6=0.f,a7=0.f;
  float den = 0.f;
  #pragma unroll 2
  for(int e = e0; e < e1; e += 3){
    int ee = e + ((slot < 3) ? slot : 2);
    int ec = (ee < e1) ? ee : (e1 - 1);       // clamped safe index
    int s = ssrc[ec];
    bool act = (slot < 3) && (ee < e1);
    float w = act ? __expf(leaky(el[s*4 + head] + ern)) : 0.f;
    uint4 q = feat4[(size_t)s*20 + wl];
    a0 = fmaf(w, bf_lo(q.x), a0); a1 = fmaf(w, bf_hi(q.x), a1);
    a2 = fmaf(w, bf_lo(q.y), a2); a3 = fmaf(w, bf_hi(q.y), a3);
    a4 = fmaf(w, bf_lo(q.z), a4); a5 = fmaf(w, bf_hi(q.z), a5);
    a6 = fmaf(w, bf_lo(q.w), a6); a7 = fmaf(w, bf_hi(q.w), a7);
    den += w;
  }
  // slot-reduce: lane += lane+20, lane+40 (results valid on lanes 0-19)
  {
    float t1, t2;
    t1 = __shfl(a0, lane+20); t2 = __shfl(a0, lane+40); a0 += t1 + t2;
    t1 = __shfl(a1, lane+20); t2 = __shfl(a1, lane+40); a1 += t1 + t2;
    t1 = __shfl(a2, lane+20); t2 = __shfl(a2, lane+40); a2 += t1 + t2;
    t1 = __shfl(a3, lane+20); t2 = __shfl(a3, lane+40); a3 += t1 + t2;
    t1 = __shfl(a4, lane+20); t2 = __shfl(a4, lane+40); a4 += t1 + t2;
    t1 = __shfl(a5, lane+20); t2 = __shfl(a5, lane+40); a5 += t1 + t2;
    t1 = __shfl(a6, lane+20); t2 = __shfl(a6, lane+40); a6 += t1 + t2;
    t1 = __shfl(a7, lane+20); t2 = __shfl(a7, lane+40); a7 += t1 + t2;
    t1 = __shfl(den, lane+20); t2 = __shfl(den, lane+40); den += t1 + t2;
  }
  if(slot == 0){                       // lanes 0-19
    float inv = 1.f / fmaxf(den, 1e-9f);
    float4 ba = *(const float4*)&bias[wl*8];
    float4 bb = *(const float4*)&bias[wl*8+4];
    float o[8];
    o[0] = a0*inv + ba.x; o[1] = a1*inv + ba.y; o[2] = a2*inv + ba.z; o[3] = a3*inv + ba.w;
    o[4] = a4*inv + bb.x; o[5] = a5*inv + bb.y; o[6] = a6*inv + bb.z; o[7] = a7*inv + bb.w;
    // head-mean: class c lives on lanes {c/8 + 5h}; tree: +5 then +10
    #pragma unroll
    for(int j=0;j<8;j++){
      float t = __shfl(o[j], lane+5);  o[j] += t;
      t       = __shfl(o[j], lane+10); o[j] += t;
    }
    if(wl < 5){
      float4 r0, r1;
      r0.x = 0.25f*o[0]; r0.y = 0.25f*o[1]; r0.z = 0.25f*o[2]; r0.w = 0.25f*o[3];
      r1.x = 0.25f*o[4]; r1.y = 0.25f*o[5]; r1.z = 0.25f*o[6]; r1.w = 0.25f*o[7];
      *(float4*)&logits[(size_t)n*40 + wl*8]     = r0;
      *(float4*)&logits[(size_t)n*40 + wl*8 + 4] = r1;
    }
  }
}

extern "C" void kernel_launch(void* const* d_in, const int* in_sizes, int n_in,
                              void* d_out, int out_size, void* d_ws, size_t ws_size,
                              hipStream_t stream){
  const float* x   = (const float*)d_in[0];
  const int*   eix = (const int*)  d_in[1];
  const float* W0  = (const float*)d_in[2];
  const float* al0 = (const float*)d_in[3];
  const float* ar0 = (const float*)d_in[4];
  const float* b0  = (const float*)d_in[5];
  const float* W1  = (const float*)d_in[6];
  const float* al1 = (const float*)d_in[7];
  const float* ar1 = (const float*)d_in[8];
  const float* b1  = (const float*)d_in[9];
  const float* W2  = (const float*)d_in[10];
  const float* al2 = (const float*)d_in[11];
  const float* ar2 = (const float*)d_in[12];
  const float* b2  = (const float*)d_in[13];
  float* logits = (float*)d_out;

  const int N = in_sizes[0] / 256;   // 50000
  const int E = in_sizes[1] / 2;     // 800000
  const int* src = eix;
  const int* dst = eix + E;
  const int nb = (N + 1023) / 1024;

  char* ws = (char*)d_ws;
  auto alloc = [&](size_t bytes)->char*{
    char* p = ws; ws += (bytes + 255) & ~(size_t)255; return p;
  };
  const int nblocksM = (N + 127)/128;
  const int Mpad = nblocksM * 128;
  const size_t apackElems = (size_t)Mpad * 256;
  int*   counts    = (int*)  alloc((size_t)N*4);
  int*   offsets   = (int*)  alloc((size_t)(N+1)*4);
  int*   cursor    = (int*)  alloc((size_t)N*4);
  int*   blocksums = (int*)  alloc((size_t)nb*4);
  int*   ssrc      = (int*)  alloc((size_t)E*4);
  __hip_bfloat16* bufF = (__hip_bfloat16*)alloc((size_t)N*256*2);   // gemm output (bf16, row-major)
  ushortT* Hh      = (ushortT*)alloc(apackElems*2);                  // A hi plane [t][Mpad][32]
  ushortT* Hl      = (ushortT*)alloc(apackElems*2);                  // A lo plane
  float* el_buf    = (float*)alloc((size_t)N*4*4);
  float* er_buf    = (float*)alloc((size_t)N*4*4);
  ushortT* Wph0 = (ushortT*)alloc(16*8*64*8*2);
  ushortT* Wpl0 = (ushortT*)alloc(16*8*64*8*2);
  ushortT* Wph1 = (ushortT*)alloc(16*8*64*8*2);
  ushortT* Wpl1 = (ushortT*)alloc(16*8*64*8*2);
  ushortT* Wph2 = (ushortT*)alloc(16*8*64*8*2);
  ushortT* Wpl2 = (ushortT*)alloc(16*8*64*8*2);

  // sort edges by dst (graph fixed across layers — one sort per call)
  hipMemsetAsync(counts, 0, (size_t)N*4, stream);
  hist_kernel   <<<(E+255)/256, 256, 0, stream>>>(dst, E, counts);
  scan1_kernel  <<<nb, 1024, 0, stream>>>(counts, N, offsets, blocksums);
  scan3_kernel  <<<nb, 1024, 0, stream>>>(offsets, blocksums, N, E, cursor);
  scatter_kernel<<<(E+255)/256, 256, 0, stream>>>(src, dst, E, cursor, ssrc);

  // fused packing: x-split + 3x W-split in ONE dispatch
  int xblocks = (8*Mpad + 255)/256;
  pack_all<<<xblocks + 96, 256, 0, stream>>>(x, N, Mpad, xblocks, Hh, Hl,
                                             W0, W1, W2, Wph0, Wpl0, Wph1, Wpl1, Wph2, Wpl2);

  int ggBlocks = Mpad / 32;        // block = 32 rows x full-N; A-tile LDS-staged
  int aggGrid  = (N+3)/4;
  // layer 0 (el/er fused in gemm epilogue; edge weights fused in agg)
  gemm_packed<<<ggBlocks, 256, 0, stream>>>(Hh, Hl, Wph0, Wpl0, (ushortT*)bufF, N, Mpad, 256, 16, al0, ar0, el_buf, er_buf);
  agg_kernel<<<aggGrid, 256, 0, stream>>>((const uint4*)bufF, el_buf, er_buf, offsets, ssrc, b0, Hh, Hl, N, Mpad);
  // layer 1
  gemm_packed<<<ggBlocks, 256, 0, stream>>>(Hh, Hl, Wph1, Wpl1, (ushortT*)bufF, N, Mpad, 256, 16, al1, ar1, el_buf, er_buf);
  agg_kernel<<<aggGrid, 256, 0, stream>>>((const uint4*)bufF, el_buf, er_buf, offsets, ssrc, b1, Hh, Hl, N, Mpad);
  // layer 2 (ntiles=10: waves 2/3 skip B-loads+MFMA beyond col 160)
  gemm_packed<<<ggBlocks, 256, 0, stream>>>(Hh, Hl, Wph2, Wpl2, (ushortT*)bufF, N, Mpad, 160, 10, nullptr, nullptr, nullptr, nullptr);
  attn_proj_bf<<<aggGrid, 256, 0, stream>>>((const ushortT*)bufF, al2, ar2, el_buf, er_buf, N);
  agg2_kernel<<<aggGrid, 256, 0, stream>>>((const uint4*)bufF, el_buf, er_buf, offsets, ssrc, b2, logits, N);
}